// Round 4
// baseline (354.802 us; speedup 1.0000x reference)
//
#include <hip/hip_runtime.h>

typedef unsigned short ushort_t;
typedef __attribute__((ext_vector_type(8))) short bf16x8;     // 8 bf16 (4 VGPRs)
typedef __attribute__((ext_vector_type(4))) float f32x4;
typedef __attribute__((ext_vector_type(4))) unsigned short us4;

#define DM 2048
#define RK 64

__device__ __forceinline__ ushort_t f2b(float f) {
    union { float f; unsigned u; } x; x.f = f;
    unsigned r = x.u + 0x7fff + ((x.u >> 16) & 1);   // RNE
    return (ushort_t)(r >> 16);
}

// ---------------- P1: Mmid[64][64] = butterfly(Wbs) @ Wcr ----------------
__global__ void k_p1(const float* __restrict__ Wbs, const float* __restrict__ Af,
                     const float* __restrict__ Wcr, float* __restrict__ Mmid) {
    __shared__ float X[64 * 256];          // 64 KB, becomes T1
    const int tid = threadIdx.x;
#pragma unroll
    for (int i = 0; i < 16; ++i) {
        int e = (i * 256 + tid) * 4;
        *(float4*)&X[e] = *(const float4*)&Wbs[e];
    }
    __syncthreads();
#pragma unroll
    for (int l = 0; l < 8; ++l) {
        const int bit = 1 << (7 - l);
        const float a00 = Af[l * 4 + 0], a01 = Af[l * 4 + 1];
        const float a10 = Af[l * 4 + 2], a11 = Af[l * 4 + 3];
#pragma unroll 4
        for (int p = 0; p < 32; ++p) {
            int pid = p * 256 + tid;
            int row = pid >> 7;
            int off = pid & 127;
            int lo = off & (bit - 1);
            int n0 = ((off ^ lo) << 1) | lo;
            int n1 = n0 | bit;
            float x0 = X[row * 256 + n0], x1 = X[row * 256 + n1];
            X[row * 256 + n0] = x0 * a00 + x1 * a10;
            X[row * 256 + n1] = x0 * a01 + x1 * a11;
        }
        __syncthreads();
    }
    int g = blockIdx.x * 256 + tid;
    int r1 = g >> 6, r2 = g & 63;
    float s = 0.f;
#pragma unroll 8
    for (int n = 0; n < 256; ++n) s += X[r1 * 256 + n] * Wcr[n * 64 + r2];
    Mmid[g] = s;
}

// ---------------- P2: WeffT[64][2048] = (Wbr @ Mmid)^T, WcT[2048][64] = Wcm^T ----
__global__ void k_p2(const float* __restrict__ Wbr, const float* __restrict__ Mmid,
                     const float* __restrict__ Wcm,
                     ushort_t* __restrict__ WeffT, ushort_t* __restrict__ WcT) {
    const int b = blockIdx.x, tid = threadIdx.x;
    if (b < 32) {
        __shared__ float LW[64][65];
        __shared__ float LM[64 * 64];
#pragma unroll
        for (int i = 0; i < 4; ++i) {
            int e = (i * 256 + tid) * 4;
            int kk = e >> 6, r = e & 63;
            float4 v = *(const float4*)&Wbr[(size_t)b * 4096 + e];
            LW[kk][r] = v.x; LW[kk][r + 1] = v.y; LW[kk][r + 2] = v.z; LW[kk][r + 3] = v.w;
        }
#pragma unroll
        for (int i = 0; i < 4; ++i) {
            int e = (i * 256 + tid) * 4;
            *(float4*)&LM[e] = *(const float4*)&Mmid[e];
        }
        __syncthreads();
        int kk = tid & 63, n0 = (tid >> 6) * 16;
        float acc[16];
#pragma unroll
        for (int j = 0; j < 16; ++j) acc[j] = 0.f;
        for (int r = 0; r < 64; ++r) {
            float wv = LW[kk][r];
            const float* mrow = &LM[r * 64 + n0];
            float4 m0 = *(const float4*)(mrow);
            float4 m1 = *(const float4*)(mrow + 4);
            float4 m2 = *(const float4*)(mrow + 8);
            float4 m3 = *(const float4*)(mrow + 12);
            acc[0] += wv * m0.x; acc[1] += wv * m0.y; acc[2] += wv * m0.z; acc[3] += wv * m0.w;
            acc[4] += wv * m1.x; acc[5] += wv * m1.y; acc[6] += wv * m1.z; acc[7] += wv * m1.w;
            acc[8] += wv * m2.x; acc[9] += wv * m2.y; acc[10] += wv * m2.z; acc[11] += wv * m2.w;
            acc[12] += wv * m3.x; acc[13] += wv * m3.y; acc[14] += wv * m3.z; acc[15] += wv * m3.w;
        }
#pragma unroll
        for (int j = 0; j < 16; ++j)
            WeffT[(size_t)(n0 + j) * DM + b * 64 + kk] = f2b(acc[j]);
    } else {
        __shared__ float LT[64][65];
        const int n0 = (b - 32) * 64;
#pragma unroll
        for (int i = 0; i < 4; ++i) {
            int e = (i * 256 + tid) * 4;
            int k = e >> 6, nn = e & 63;
            float4 v = *(const float4*)&Wcm[(size_t)k * DM + n0 + nn];
            LT[k][nn] = v.x; LT[k][nn + 1] = v.y; LT[k][nn + 2] = v.z; LT[k][nn + 3] = v.w;
        }
        __syncthreads();
#pragma unroll
        for (int i = 0; i < 4; ++i) {
            int e = (i * 256 + tid) * 4;
            int nn = e >> 6, k = e & 63;
            us4 o;
            o.x = f2b(LT[k][nn]); o.y = f2b(LT[k + 1][nn]);
            o.z = f2b(LT[k + 2][nn]); o.w = f2b(LT[k + 3][nn]);
            *(us4*)&WcT[(size_t)(n0 + nn) * RK + k] = o;
        }
    }
}

// ---------------- main: out = (u @ W_eff) @ W_c_model + D*u ----------------
// 1024 blocks x 4 waves, 16 rows/block. Explicit 2-deep software pipeline in
// both phases: next iteration's loads issued into named registers BEFORE the
// current iteration's MFMAs, forcing deep in-flight load queues (the round-2
// kernel compiled to 48 VGPRs => shallow pipelining => 2.3 TB/s ceiling).
// __launch_bounds__(256,4): up to 128 VGPR at 16 waves/CU.
__global__ __launch_bounds__(256, 4) void k_main(const float* __restrict__ u,
                                                 const ushort_t* __restrict__ WeffT,
                                                 const ushort_t* __restrict__ WcT,
                                                 const float* __restrict__ Dvec,
                                                 float* __restrict__ out) {
    __shared__ float red[4][16][68];       // 17.4 KB partial-t
    __shared__ ushort_t tsh[16 * 72];      // t bf16, stride 72

    const int tid = threadIdx.x;
    const int w = tid >> 6;                // wave 0..3
    const int lane = tid & 63;
    const int m16 = lane & 15;
    const int quad = lane >> 4;
    const size_t row0 = (size_t)blockIdx.x * 16;
    const float* ub = u + row0 * DM;

    // ---- phase 1: K-slice [w*512, +512), 16 steps of K=32, 2-deep pipeline ----
    const float* ap = ub + m16 * DM + w * 512 + quad * 8;
    const ushort_t* bp = WeffT + (size_t)m16 * DM + w * 512 + quad * 8;

    f32x4 acc0 = {0.f, 0.f, 0.f, 0.f}, acc1 = acc0, acc2 = acc0, acc3 = acc0;
    float4 u0c = *(const float4*)(ap);
    float4 u1c = *(const float4*)(ap + 4);
    bf16x8 b0c = *(const bf16x8*)(bp);
    bf16x8 b1c = *(const bf16x8*)(bp + 16 * DM);
    bf16x8 b2c = *(const bf16x8*)(bp + 32 * DM);
    bf16x8 b3c = *(const bf16x8*)(bp + 48 * DM);
#pragma unroll
    for (int kk = 0; kk < 16; ++kk) {
        float4 u0n, u1n; bf16x8 b0n, b1n, b2n, b3n;
        if (kk < 15) {                      // issue next-step loads FIRST
            const int k0 = (kk + 1) * 32;
            u0n = *(const float4*)(ap + k0);
            u1n = *(const float4*)(ap + k0 + 4);
            b0n = *(const bf16x8*)(bp + k0);
            b1n = *(const bf16x8*)(bp + 16 * DM + k0);
            b2n = *(const bf16x8*)(bp + 32 * DM + k0);
            b3n = *(const bf16x8*)(bp + 48 * DM + k0);
        }
        bf16x8 a;
        a[0] = (short)f2b(u0c.x); a[1] = (short)f2b(u0c.y);
        a[2] = (short)f2b(u0c.z); a[3] = (short)f2b(u0c.w);
        a[4] = (short)f2b(u1c.x); a[5] = (short)f2b(u1c.y);
        a[6] = (short)f2b(u1c.z); a[7] = (short)f2b(u1c.w);
        acc0 = __builtin_amdgcn_mfma_f32_16x16x32_bf16(a, b0c, acc0, 0, 0, 0);
        acc1 = __builtin_amdgcn_mfma_f32_16x16x32_bf16(a, b1c, acc1, 0, 0, 0);
        acc2 = __builtin_amdgcn_mfma_f32_16x16x32_bf16(a, b2c, acc2, 0, 0, 0);
        acc3 = __builtin_amdgcn_mfma_f32_16x16x32_bf16(a, b3c, acc3, 0, 0, 0);
        if (kk < 15) {
            u0c = u0n; u1c = u1n;
            b0c = b0n; b1c = b1n; b2c = b2n; b3c = b3n;
        }
    }
    // C layout: row = quad*4+i, col(n) = 16*j + m16
#pragma unroll
    for (int i = 0; i < 4; ++i) {
        red[w][quad * 4 + i][ 0 + m16] = acc0[i];
        red[w][quad * 4 + i][16 + m16] = acc1[i];
        red[w][quad * 4 + i][32 + m16] = acc2[i];
        red[w][quad * 4 + i][48 + m16] = acc3[i];
    }
    __syncthreads();

    // ---- reduce: 1024 entries / 256 threads = 4 each ----
    {
        const int row = tid >> 4, c0 = (tid & 15) * 4;
        float4 s0 = *(const float4*)&red[0][row][c0];
        float4 s1 = *(const float4*)&red[1][row][c0];
        float4 s2 = *(const float4*)&red[2][row][c0];
        float4 s3 = *(const float4*)&red[3][row][c0];
        us4 o;
        o.x = f2b(s0.x + s1.x + s2.x + s3.x);
        o.y = f2b(s0.y + s1.y + s2.y + s3.y);
        o.z = f2b(s0.z + s1.z + s2.z + s3.z);
        o.w = f2b(s0.w + s1.w + s2.w + s3.w);
        *(us4*)&tsh[row * 72 + c0] = o;
    }
    __syncthreads();

    // ---- phase 2: wave w owns cols [w*512, +512), 2-deep pipeline ----
    bf16x8 ta0 = *(const bf16x8*)&tsh[m16 * 72 + quad * 8];
    bf16x8 ta1 = *(const bf16x8*)&tsh[m16 * 72 + 32 + quad * 8];
    const ushort_t* wcb = WcT + (size_t)(w * 512 + m16) * RK + quad * 8;
    const float* u2 = ub + m16 * DM + w * 512 + quad * 4;
    const float* dp = Dvec + w * 512 + quad * 4;
    float* op = out + (row0 + m16) * DM + w * 512 + quad * 4;

    bf16x8 wb0c = *(const bf16x8*)(wcb);
    bf16x8 wb1c = *(const bf16x8*)(wcb + 32);
    float4 uvc = *(const float4*)(u2);
    float4 dvc = *(const float4*)(dp);
#pragma unroll 4
    for (int nt = 0; nt < 32; ++nt) {
        bf16x8 wb0n, wb1n; float4 uvn, dvn;
        if (nt < 31) {                      // issue next-step loads FIRST
            const ushort_t* bp2 = wcb + (nt + 1) * 16 * RK;
            wb0n = *(const bf16x8*)(bp2);
            wb1n = *(const bf16x8*)(bp2 + 32);
            uvn = *(const float4*)(u2 + (nt + 1) * 16);
            dvn = *(const float4*)(dp + (nt + 1) * 16);
        }
        f32x4 o = {0.f, 0.f, 0.f, 0.f};
        // A = WcT rows (out-cols), B = t rows (out-rows):
        // lane gets out[row0+m16][w*512 + nt*16 + quad*4 + i] -> float4 store
        o = __builtin_amdgcn_mfma_f32_16x16x32_bf16(wb0c, ta0, o, 0, 0, 0);
        o = __builtin_amdgcn_mfma_f32_16x16x32_bf16(wb1c, ta1, o, 0, 0, 0);
        f32x4 st;
        st.x = o[0] + dvc.x * uvc.x;
        st.y = o[1] + dvc.y * uvc.y;
        st.z = o[2] + dvc.z * uvc.z;
        st.w = o[3] + dvc.w * uvc.w;
        __builtin_nontemporal_store(st, (f32x4*)(op + nt * 16));
        if (nt < 31) {
            wb0c = wb0n; wb1c = wb1n; uvc = uvn; dvc = dvn;
        }
    }
}

extern "C" void kernel_launch(void* const* d_in, const int* in_sizes, int n_in,
                              void* d_out, int out_size, void* d_ws, size_t ws_size,
                              hipStream_t stream) {
    (void)in_sizes; (void)n_in; (void)out_size; (void)ws_size;
    const float* u   = (const float*)d_in[0];
    const float* Af  = (const float*)d_in[1];
    const float* Wbr = (const float*)d_in[2];
    const float* Wbs = (const float*)d_in[3];
    const float* Wcr = (const float*)d_in[4];
    const float* Wcm = (const float*)d_in[5];
    const float* Dv  = (const float*)d_in[6];
    float* out = (float*)d_out;

    char* ws = (char*)d_ws;
    float*    Mmid  = (float*)(ws + 0);            // 64*64*4    =   16384
    ushort_t* WeffT = (ushort_t*)(ws + 16384);     // 64*2048*2  =  262144
    ushort_t* WcT   = (ushort_t*)(ws + 278528);    // 2048*64*2  =  262144

    k_p1<<<16, 256, 0, stream>>>(Wbs, Af, Wcr, Mmid);
    k_p2<<<64, 256, 0, stream>>>(Wbr, Mmid, Wcm, WeffT, WcT);
    k_main<<<1024, 256, 0, stream>>>(u, WeffT, WcT, Dv, out);
}

// Round 5
// 337.666 us; speedup vs baseline: 1.0507x; 1.0507x over previous
//
#include <hip/hip_runtime.h>

typedef unsigned short ushort_t;
typedef __attribute__((ext_vector_type(8))) short bf16x8;     // 8 bf16 (4 VGPRs)
typedef __attribute__((ext_vector_type(4))) float f32x4;
typedef __attribute__((ext_vector_type(4))) unsigned short us4;

#define DM 2048
#define RK 64

__device__ __forceinline__ ushort_t f2b(float f) {
    union { float f; unsigned u; } x; x.f = f;
    unsigned r = x.u + 0x7fff + ((x.u >> 16) & 1);   // RNE
    return (ushort_t)(r >> 16);
}

// ---------------- P1: Mmid[64][64] = butterfly(Wbs) @ Wcr ----------------
__global__ void k_p1(const float* __restrict__ Wbs, const float* __restrict__ Af,
                     const float* __restrict__ Wcr, float* __restrict__ Mmid) {
    __shared__ float X[64 * 256];          // 64 KB, becomes T1
    const int tid = threadIdx.x;
#pragma unroll
    for (int i = 0; i < 16; ++i) {
        int e = (i * 256 + tid) * 4;
        *(float4*)&X[e] = *(const float4*)&Wbs[e];
    }
    __syncthreads();
#pragma unroll
    for (int l = 0; l < 8; ++l) {
        const int bit = 1 << (7 - l);
        const float a00 = Af[l * 4 + 0], a01 = Af[l * 4 + 1];
        const float a10 = Af[l * 4 + 2], a11 = Af[l * 4 + 3];
#pragma unroll 4
        for (int p = 0; p < 32; ++p) {
            int pid = p * 256 + tid;
            int row = pid >> 7;
            int off = pid & 127;
            int lo = off & (bit - 1);
            int n0 = ((off ^ lo) << 1) | lo;
            int n1 = n0 | bit;
            float x0 = X[row * 256 + n0], x1 = X[row * 256 + n1];
            X[row * 256 + n0] = x0 * a00 + x1 * a10;
            X[row * 256 + n1] = x0 * a01 + x1 * a11;
        }
        __syncthreads();
    }
    int g = blockIdx.x * 256 + tid;
    int r1 = g >> 6, r2 = g & 63;
    float s = 0.f;
#pragma unroll 8
    for (int n = 0; n < 256; ++n) s += X[r1 * 256 + n] * Wcr[n * 64 + r2];
    Mmid[g] = s;
}

// ---------------- P2: WeffT[64][2048] = (Wbr @ Mmid)^T, WcT[2048][64] = Wcm^T ----
__global__ void k_p2(const float* __restrict__ Wbr, const float* __restrict__ Mmid,
                     const float* __restrict__ Wcm,
                     ushort_t* __restrict__ WeffT, ushort_t* __restrict__ WcT) {
    const int b = blockIdx.x, tid = threadIdx.x;
    if (b < 32) {
        __shared__ float LW[64][65];
        __shared__ float LM[64 * 64];
#pragma unroll
        for (int i = 0; i < 4; ++i) {
            int e = (i * 256 + tid) * 4;
            int kk = e >> 6, r = e & 63;
            float4 v = *(const float4*)&Wbr[(size_t)b * 4096 + e];
            LW[kk][r] = v.x; LW[kk][r + 1] = v.y; LW[kk][r + 2] = v.z; LW[kk][r + 3] = v.w;
        }
#pragma unroll
        for (int i = 0; i < 4; ++i) {
            int e = (i * 256 + tid) * 4;
            *(float4*)&LM[e] = *(const float4*)&Mmid[e];
        }
        __syncthreads();
        int kk = tid & 63, n0 = (tid >> 6) * 16;
        float acc[16];
#pragma unroll
        for (int j = 0; j < 16; ++j) acc[j] = 0.f;
        for (int r = 0; r < 64; ++r) {
            float wv = LW[kk][r];
            const float* mrow = &LM[r * 64 + n0];
            float4 m0 = *(const float4*)(mrow);
            float4 m1 = *(const float4*)(mrow + 4);
            float4 m2 = *(const float4*)(mrow + 8);
            float4 m3 = *(const float4*)(mrow + 12);
            acc[0] += wv * m0.x; acc[1] += wv * m0.y; acc[2] += wv * m0.z; acc[3] += wv * m0.w;
            acc[4] += wv * m1.x; acc[5] += wv * m1.y; acc[6] += wv * m1.z; acc[7] += wv * m1.w;
            acc[8] += wv * m2.x; acc[9] += wv * m2.y; acc[10] += wv * m2.z; acc[11] += wv * m2.w;
            acc[12] += wv * m3.x; acc[13] += wv * m3.y; acc[14] += wv * m3.z; acc[15] += wv * m3.w;
        }
#pragma unroll
        for (int j = 0; j < 16; ++j)
            WeffT[(size_t)(n0 + j) * DM + b * 64 + kk] = f2b(acc[j]);
    } else {
        __shared__ float LT[64][65];
        const int n0 = (b - 32) * 64;
#pragma unroll
        for (int i = 0; i < 4; ++i) {
            int e = (i * 256 + tid) * 4;
            int k = e >> 6, nn = e & 63;
            float4 v = *(const float4*)&Wcm[(size_t)k * DM + n0 + nn];
            LT[k][nn] = v.x; LT[k][nn + 1] = v.y; LT[k][nn + 2] = v.z; LT[k][nn + 3] = v.w;
        }
        __syncthreads();
#pragma unroll
        for (int i = 0; i < 4; ++i) {
            int e = (i * 256 + tid) * 4;
            int nn = e >> 6, k = e & 63;
            us4 o;
            o.x = f2b(LT[k][nn]); o.y = f2b(LT[k + 1][nn]);
            o.z = f2b(LT[k + 2][nn]); o.w = f2b(LT[k + 3][nn]);
            *(us4*)&WcT[(size_t)(n0 + nn) * RK + k] = o;
        }
    }
}

// ---------------- main: out = (u @ W_eff) @ W_c_model + D*u ----------------
// 1024 blocks x 1 wave (64 thr), 16 rows/block, fully wave-independent.
// Phase 1: u staged fp32 -> LDS via global_load_lds (async DMA the compiler
// can't un-pipeline), double-buffered 8KB tiles (K=128), one tile prefetched
// ahead => 8KB in flight per wave. LDS XOR-swizzle (chunk ^= row ^ (row&2)<<3)
// applied to BOTH the global source addr and the ds_read addr (linear dest
// requirement of global_load_lds) -> 2-way banks instead of 16-way.
// WeffT frags loaded to regs BEFORE the stage-issue so derived waits are
// vmcnt(24)/vmcnt(8), never a full drain.
__global__ __launch_bounds__(64, 1) void k_main(const float* __restrict__ u,
                                                const ushort_t* __restrict__ WeffT,
                                                const ushort_t* __restrict__ WcT,
                                                const float* __restrict__ Dvec,
                                                float* __restrict__ out) {
    __shared__ float sbuf[2][16 * 128];    // 2 x 8 KB u tiles (fp32, swizzled)
    __shared__ ushort_t tsh[16 * 72];      // t bf16, stride 72

    const int lane = threadIdx.x;          // 0..63
    const int m16 = lane & 15;
    const int quad = lane >> 4;
    const size_t row0 = (size_t)blockIdx.x * 16;
    const float* ub = u + row0 * DM;

    // stage tile S (cols S*128..+128, rows 0..15) into sbuf[BUF]; linear LDS
    // dest (uniform base + lane*16), inverse-swizzled global source.
#define STAGE(BUF, S)                                                          \
    {                                                                          \
        _Pragma("unroll")                                                      \
        for (int j = 0; j < 8; ++j) {                                          \
            int srow = j * 2 + (lane >> 5);                                    \
            int p = lane & 31;                                                 \
            int g = p ^ srow ^ ((srow & 2) << 3);                              \
            const float* gp = ub + (size_t)srow * DM + (S) * 128 + g * 4;      \
            __builtin_amdgcn_global_load_lds(                                  \
                (const __attribute__((address_space(1))) void*)gp,             \
                (__attribute__((address_space(3))) void*)&sbuf[BUF][j * 256],  \
                16, 0, 0);                                                     \
        }                                                                      \
    }

    f32x4 acc0 = {0.f, 0.f, 0.f, 0.f}, acc1 = acc0, acc2 = acc0, acc3 = acc0;

    STAGE(0, 0);
    for (int s = 0; s < 16; ++s) {
        const int cur = s & 1;
        // WeffT fragments for this K-tile (16 loads, L2-resident) issued FIRST
        bf16x8 wf0[4], wf1[4], wf2[4], wf3[4];
#pragma unroll
        for (int ks = 0; ks < 4; ++ks) {
            const ushort_t* wp = WeffT + (size_t)m16 * DM + s * 128 + ks * 32 + quad * 8;
            wf0[ks] = *(const bf16x8*)(wp);
            wf1[ks] = *(const bf16x8*)(wp + 16 * DM);
            wf2[ks] = *(const bf16x8*)(wp + 32 * DM);
            wf3[ks] = *(const bf16x8*)(wp + 48 * DM);
        }
        if (s < 15) STAGE(cur ^ 1, s + 1);   // prefetch next tile (stays in flight)

#pragma unroll
        for (int ks = 0; ks < 4; ++ks) {
            const int c0 = ks * 8 + quad * 2;
            const int swz = m16 ^ ((m16 & 2) << 3);
            f32x4 va = *(const f32x4*)&sbuf[cur][m16 * 128 + (c0 ^ swz) * 4];
            f32x4 vb = *(const f32x4*)&sbuf[cur][m16 * 128 + ((c0 + 1) ^ swz) * 4];
            bf16x8 a;
            a[0] = (short)f2b(va[0]); a[1] = (short)f2b(va[1]);
            a[2] = (short)f2b(va[2]); a[3] = (short)f2b(va[3]);
            a[4] = (short)f2b(vb[0]); a[5] = (short)f2b(vb[1]);
            a[6] = (short)f2b(vb[2]); a[7] = (short)f2b(vb[3]);
            acc0 = __builtin_amdgcn_mfma_f32_16x16x32_bf16(a, wf0[ks], acc0, 0, 0, 0);
            acc1 = __builtin_amdgcn_mfma_f32_16x16x32_bf16(a, wf1[ks], acc1, 0, 0, 0);
            acc2 = __builtin_amdgcn_mfma_f32_16x16x32_bf16(a, wf2[ks], acc2, 0, 0, 0);
            acc3 = __builtin_amdgcn_mfma_f32_16x16x32_bf16(a, wf3[ks], acc3, 0, 0, 0);
        }
    }

    // t -> LDS (bf16). C layout: row = quad*4+i, col(n) = 16*j + m16.
#pragma unroll
    for (int i = 0; i < 4; ++i) {
        tsh[(quad * 4 + i) * 72 +  0 + m16] = f2b(acc0[i]);
        tsh[(quad * 4 + i) * 72 + 16 + m16] = f2b(acc1[i]);
        tsh[(quad * 4 + i) * 72 + 32 + m16] = f2b(acc2[i]);
        tsh[(quad * 4 + i) * 72 + 48 + m16] = f2b(acc3[i]);
    }
    __syncthreads();                        // single-wave block: cheap

    // ---- phase 2: this wave streams all 2048 out-cols of its 16 rows ----
    bf16x8 ta0 = *(const bf16x8*)&tsh[m16 * 72 + quad * 8];
    bf16x8 ta1 = *(const bf16x8*)&tsh[m16 * 72 + 32 + quad * 8];
    const ushort_t* wcb = WcT + (size_t)m16 * RK + quad * 8;
    const float* u2 = ub + m16 * DM + quad * 4;
    const float* dp = Dvec + quad * 4;
    float* op = out + (row0 + m16) * DM + quad * 4;
#pragma unroll 8
    for (int nt = 0; nt < 128; ++nt) {
        const ushort_t* bp2 = wcb + (size_t)nt * 16 * RK;
        bf16x8 wb0 = *(const bf16x8*)(bp2);
        bf16x8 wb1 = *(const bf16x8*)(bp2 + 32);
        f32x4 o = {0.f, 0.f, 0.f, 0.f};
        // A = WcT rows (out-cols), B = t rows (out-rows):
        // lane stores out[row0+m16][nt*16 + quad*4 + i] -> float4
        o = __builtin_amdgcn_mfma_f32_16x16x32_bf16(wb0, ta0, o, 0, 0, 0);
        o = __builtin_amdgcn_mfma_f32_16x16x32_bf16(wb1, ta1, o, 0, 0, 0);
        float4 uv = *(const float4*)(u2 + nt * 16);
        float4 dv = *(const float4*)(dp + nt * 16);
        f32x4 st;
        st[0] = o[0] + dv.x * uv.x;
        st[1] = o[1] + dv.y * uv.y;
        st[2] = o[2] + dv.z * uv.z;
        st[3] = o[3] + dv.w * uv.w;
        *(f32x4*)(op + nt * 16) = st;
    }
#undef STAGE
}

extern "C" void kernel_launch(void* const* d_in, const int* in_sizes, int n_in,
                              void* d_out, int out_size, void* d_ws, size_t ws_size,
                              hipStream_t stream) {
    (void)in_sizes; (void)n_in; (void)out_size; (void)ws_size;
    const float* u   = (const float*)d_in[0];
    const float* Af  = (const float*)d_in[1];
    const float* Wbr = (const float*)d_in[2];
    const float* Wbs = (const float*)d_in[3];
    const float* Wcr = (const float*)d_in[4];
    const float* Wcm = (const float*)d_in[5];
    const float* Dv  = (const float*)d_in[6];
    float* out = (float*)d_out;

    char* ws = (char*)d_ws;
    float*    Mmid  = (float*)(ws + 0);            // 64*64*4    =   16384
    ushort_t* WeffT = (ushort_t*)(ws + 16384);     // 64*2048*2  =  262144
    ushort_t* WcT   = (ushort_t*)(ws + 278528);    // 2048*64*2  =  262144

    k_p1<<<16, 256, 0, stream>>>(Wbs, Af, Wcr, Mmid);
    k_p2<<<64, 256, 0, stream>>>(Wbr, Mmid, Wcm, WeffT, WcT);
    k_main<<<1024, 64, 0, stream>>>(u, WeffT, WcT, Dv, out);
}